// Round 4
// baseline (576.310 us; speedup 1.0000x reference)
//
#include <hip/hip_runtime.h>
#include <cmath>

#define B_ 2
#define K_ 384
#define N_ 4096
#define D_ 1024
#define H_ 150
#define L_ 12
#define NB_ 10

typedef unsigned short u16;
typedef __bf16 bf16x8 __attribute__((ext_vector_type(8)));
typedef float f32x4 __attribute__((ext_vector_type(4)));

__device__ __forceinline__ u16 f2bf(float f){
  unsigned u = __builtin_bit_cast(unsigned, f);
  unsigned r = (u + 0x7FFFu + ((u >> 16) & 1u)) >> 16;
  return (u16)r;
}
__device__ __forceinline__ float bf2f(u16 h){
  unsigned u = ((unsigned)h) << 16;
  return __builtin_bit_cast(float, u);
}
__device__ __forceinline__ int bucketf(int d){
  int da = d < 0 ? -d : d;
  if (da <= 4) return da;
  int lg = 31 - __clz(da);
  int v = lg + 3;
  return v > NB_ - 1 ? NB_ - 1 : v;
}

// ---------------- transpose fp32 (Kd x Nd) -> bf16 (Nd x Kd), out row stride = ostride
__global__ void transpose_f2bf(const float* __restrict__ in, u16* __restrict__ out,
                               int Kd, int Nd, int ostride){
  __shared__ float t[32][33];
  int bx = blockIdx.x * 32, by = blockIdx.y * 32;
  int tx = threadIdx.x, ty = threadIdx.y;
  for (int i = 0; i < 32; i += 8){
    int k = by + ty + i, n = bx + tx;
    t[ty + i][tx] = (k < Kd && n < Nd) ? in[(size_t)k * Nd + n] : 0.f;
  }
  __syncthreads();
  for (int i = 0; i < 32; i += 8){
    int n = bx + ty + i, k = by + tx;
    if (n < Nd && k < Kd) out[(size_t)n * ostride + k] = f2bf(t[tx][ty + i]);
  }
}

// ---------------- transpose bf16 (K_ x D_) -> (D_ x K_) per batch
__global__ void transpose_bf(const u16* __restrict__ in, u16* __restrict__ out){
  __shared__ u16 t[32][34];
  int b = blockIdx.z;
  const u16* I = in + (size_t)b * K_ * D_;
  u16* O = out + (size_t)b * D_ * K_;
  int bx = blockIdx.x * 32, by = blockIdx.y * 32;  // bx: d, by: k
  int tx = threadIdx.x, ty = threadIdx.y;
  for (int i = 0; i < 32; i += 8) t[ty + i][tx] = I[(size_t)(by + ty + i) * D_ + bx + tx];
  __syncthreads();
  for (int i = 0; i < 32; i += 8) O[(size_t)(bx + ty + i) * K_ + by + tx] = t[tx][ty + i];
}

// ---------------- small setup: dW[10][150] = dist_emb @ Wd + bd ; blr = [bl | br]
__global__ void small_setup(const float* __restrict__ dist_emb, const float* __restrict__ Wd,
                            const float* __restrict__ bd, const float* __restrict__ bl,
                            const float* __restrict__ br, float* __restrict__ dWg,
                            float* __restrict__ blr){
  int tid = threadIdx.x;
  for (int idx = tid; idx < NB_ * H_; idx += 256){
    int nb = idx / H_, h = idx - nb * H_;
    float s = bd[h];
    for (int dd = 0; dd < 20; ++dd) s += dist_emb[nb * 20 + dd] * Wd[dd * H_ + h];
    dWg[idx] = s;
  }
  for (int idx = tid; idx < H_; idx += 256){
    blr[idx] = bl[idx];
    blr[H_ + idx] = br[idx];
  }
}

// ---------------- fp32 -> bf16 elementwise (n divisible by 4)
__global__ void cvt_f32_bf16(const float* __restrict__ in, u16* __restrict__ out, int n){
  int idx = (blockIdx.x * 256 + threadIdx.x) * 4;
  if (idx < n){
    float4 v = *(const float4*)(in + idx);
    ushort4 o;
    o.x = f2bf(v.x); o.y = f2bf(v.y); o.z = f2bf(v.z); o.w = f2bf(v.w);
    *(ushort4*)(out + idx) = o;
  }
}

// ---------------- init lr with broadcast bias (cols 0..299 = blr, pad = 0)
__global__ void init_lr(const float* __restrict__ blr, float* __restrict__ lr){
  int idx = blockIdx.x * 256 + threadIdx.x;
  if (idx >= (B_ * K_) * 304) return;
  int col = idx % 304;
  lr[idx] = (col < 300) ? blr[col] : 0.f;
}

// ---------------- bf16 MFMA GEMM, split-K with atomic fp32 accumulation
// A given as up to 3 chunk pointers, each (M x 1024) bf16 row-major.
// BT is (N x Ktot) bf16 row-major. blockIdx.z = split s over K range [s*klen,(s+1)*klen).
// Partials accumulated via atomicAdd into Out (fp32, pre-zeroed/bias-filled), row stride ldo.
__global__ __launch_bounds__(256)
void gemm_part_atomic(const u16* __restrict__ A0, const u16* __restrict__ A1,
                      const u16* __restrict__ A2, const u16* __restrict__ BT,
                      int Nn, int Ktot, int klen,
                      float* __restrict__ Out, int ldo){
  __shared__ u16 As[64][72];
  __shared__ u16 Bs[64][72];
  int tid = threadIdx.x;
  int m0 = blockIdx.x * 64, n0 = blockIdx.y * 64;
  int s = blockIdx.z;
  int kbeg = s * klen, kend = kbeg + klen;
  int wave = tid >> 6, lane = tid & 63;
  int wm = wave >> 1, wn = wave & 1;
  int q = lane >> 4, mr = lane & 15;
  f32x4 acc[2][2] = {{{0.f,0.f,0.f,0.f},{0.f,0.f,0.f,0.f}},{{0.f,0.f,0.f,0.f},{0.f,0.f,0.f,0.f}}};
  const u16* Achunks[3] = {A0, A1, A2};
  for (int k0 = kbeg; k0 < kend; k0 += 64){
    const u16* Ap = Achunks[k0 >> 10] + (k0 & 1023);
    for (int c = tid; c < 512; c += 256){
      int row = c >> 3, c8 = c & 7;
      *(uint4*)&As[row][c8 * 8] = *(const uint4*)&Ap[(size_t)(m0 + row) * 1024 + c8 * 8];
    }
    for (int c = tid; c < 512; c += 256){
      int row = c >> 3, c8 = c & 7;
      int n = n0 + row;
      uint4 v; v.x = 0; v.y = 0; v.z = 0; v.w = 0;
      if (n < Nn) v = *(const uint4*)&BT[(size_t)n * Ktot + k0 + c8 * 8];
      *(uint4*)&Bs[row][c8 * 8] = v;
    }
    __syncthreads();
#pragma unroll
    for (int ks = 0; ks < 64; ks += 32){
      bf16x8 a0 = *(const bf16x8*)&As[wm * 32 + mr][ks + q * 8];
      bf16x8 a1 = *(const bf16x8*)&As[wm * 32 + 16 + mr][ks + q * 8];
      bf16x8 b0 = *(const bf16x8*)&Bs[wn * 32 + mr][ks + q * 8];
      bf16x8 b1 = *(const bf16x8*)&Bs[wn * 32 + 16 + mr][ks + q * 8];
      acc[0][0] = __builtin_amdgcn_mfma_f32_16x16x32_bf16(a0, b0, acc[0][0], 0, 0, 0);
      acc[0][1] = __builtin_amdgcn_mfma_f32_16x16x32_bf16(a0, b1, acc[0][1], 0, 0, 0);
      acc[1][0] = __builtin_amdgcn_mfma_f32_16x16x32_bf16(a1, b0, acc[1][0], 0, 0, 0);
      acc[1][1] = __builtin_amdgcn_mfma_f32_16x16x32_bf16(a1, b1, acc[1][1], 0, 0, 0);
    }
    __syncthreads();
  }
#pragma unroll
  for (int mt = 0; mt < 2; ++mt){
#pragma unroll
    for (int nt = 0; nt < 2; ++nt){
      int col = n0 + wn * 32 + nt * 16 + mr;
      if (col >= Nn) continue;
#pragma unroll
      for (int r = 0; r < 4; ++r){
        int row = m0 + wm * 32 + mt * 16 + q * 4 + r;
        atomicAdd(&Out[(size_t)row * ldo + col], acc[mt][nt][r]);
      }
    }
  }
}

// ---------------- epilogue over fp32 accum (ld = 1024)
// mode 1: outH = bf16(tanh(acc))
// mode 2: outH = bf16(acc)
// mode 3: g = sigmoid(acc + bias[col]); un = g*uin + (1-g)*ctxtin; outF fp32, outH bf16
__global__ __launch_bounds__(256)
void gemm_epi(const float* __restrict__ accF, int n,
              const float* __restrict__ bias, int mode,
              float* __restrict__ outF, u16* __restrict__ outH,
              const float* __restrict__ uin, const u16* __restrict__ ctxtin){
  int idx = blockIdx.x * 256 + threadIdx.x;
  if (idx >= n) return;
  float ssum = accF[idx];
  if (mode == 1){
    outH[idx] = f2bf(tanhf(ssum));
  } else if (mode == 2){
    outH[idx] = f2bf(ssum);
  } else {
    int col = idx & 1023;
    float g = 1.f / (1.f + expf(-(ssum + bias[col])));
    float uo = uin[idx];
    float ct = bf2f(ctxtin[idx]);
    float un = ct + g * (uo - ct);
    outF[idx] = un;
    outH[idx] = f2bf(un);
  }
}

// ---------------- ctxt via MFMA: c{1,2}[b,i,d] = (P{,T}[b] @ u[b])[i,d] / (sum+eps)
__global__ __launch_bounds__(256)
void ctxt_mfma(const u16* __restrict__ Pbf, const u16* __restrict__ PTbf,
               const u16* __restrict__ uT, const float* __restrict__ rowsum,
               const float* __restrict__ colsum, u16* __restrict__ c1,
               u16* __restrict__ c2){
  __shared__ u16 As[64][72];
  __shared__ u16 Bs[64][72];
  int z = blockIdx.z, b = z >> 1, which = z & 1;
  const u16* A = (which ? PTbf : Pbf) + (size_t)b * K_ * K_;
  const u16* BT = uT + (size_t)b * D_ * K_;
  const float* sums = (which ? colsum : rowsum) + b * K_;
  u16* out = which ? c2 : c1;
  int tid = threadIdx.x;
  int m0 = blockIdx.x * 64, n0 = blockIdx.y * 64;
  int wave = tid >> 6, lane = tid & 63;
  int wm = wave >> 1, wn = wave & 1;
  int q = lane >> 4, mr = lane & 15;
  f32x4 acc[2][2] = {{{0.f,0.f,0.f,0.f},{0.f,0.f,0.f,0.f}},{{0.f,0.f,0.f,0.f},{0.f,0.f,0.f,0.f}}};
  for (int k0 = 0; k0 < K_; k0 += 64){
    for (int c = tid; c < 512; c += 256){
      int row = c >> 3, c8 = c & 7;
      *(uint4*)&As[row][c8 * 8] = *(const uint4*)&A[(size_t)(m0 + row) * K_ + k0 + c8 * 8];
    }
    for (int c = tid; c < 512; c += 256){
      int row = c >> 3, c8 = c & 7;
      *(uint4*)&Bs[row][c8 * 8] = *(const uint4*)&BT[(size_t)(n0 + row) * K_ + k0 + c8 * 8];
    }
    __syncthreads();
#pragma unroll
    for (int ks = 0; ks < 64; ks += 32){
      bf16x8 a0 = *(const bf16x8*)&As[wm * 32 + mr][ks + q * 8];
      bf16x8 a1 = *(const bf16x8*)&As[wm * 32 + 16 + mr][ks + q * 8];
      bf16x8 b0 = *(const bf16x8*)&Bs[wn * 32 + mr][ks + q * 8];
      bf16x8 b1 = *(const bf16x8*)&Bs[wn * 32 + 16 + mr][ks + q * 8];
      acc[0][0] = __builtin_amdgcn_mfma_f32_16x16x32_bf16(a0, b0, acc[0][0], 0, 0, 0);
      acc[0][1] = __builtin_amdgcn_mfma_f32_16x16x32_bf16(a0, b1, acc[0][1], 0, 0, 0);
      acc[1][0] = __builtin_amdgcn_mfma_f32_16x16x32_bf16(a1, b0, acc[1][0], 0, 0, 0);
      acc[1][1] = __builtin_amdgcn_mfma_f32_16x16x32_bf16(a1, b1, acc[1][1], 0, 0, 0);
    }
    __syncthreads();
  }
#pragma unroll
  for (int mt = 0; mt < 2; ++mt){
#pragma unroll
    for (int nt = 0; nt < 2; ++nt){
      int col = n0 + wn * 32 + nt * 16 + mr;
#pragma unroll
      for (int r = 0; r < 4; ++r){
        int row = m0 + wm * 32 + mt * 16 + q * 4 + r;
        float w = 1.f / (sums[row] + 1e-7f);
        out[((size_t)(b * K_ + row)) * D_ + col] = f2bf(acc[mt][nt][r] * w);
      }
    }
  }
}

// ---------------- scorer (MFMA, v2): scores[b,i,j,l] (+)= relu(l_i + r_j + dW[bk]) @ Wo + bo
// grid (K, 2, B): blockIdx.y selects a 192-wide j-half (3 chunks of 64).
// Buckets precomputed once per block; build loop has no division (jj=tid>>2, 19 pairs/thread).
__global__ __launch_bounds__(256)
void scorer_kernel(const float* __restrict__ lr, const float* __restrict__ dWg,
                   const float* __restrict__ Wo, const float* __restrict__ bo,
                   const int* __restrict__ span_begin, const int* __restrict__ span_end,
                   float* __restrict__ scores, int accumulate){
  __shared__ float ldw[NB_ * 160];
  __shared__ u16 wo_s[16][168];
  __shared__ u16 h_s[64][168];
  __shared__ int bks[192];
  int i = blockIdx.x, jhalf = blockIdx.y, b = blockIdx.z;
  int tid = threadIdx.x;
  int row_i = b * K_ + i;
  int se = span_end[row_i];
  // stage ldw = l_i + dW (zero pad t>=150)
  for (int e = tid; e < NB_ * 160; e += 256){
    int nb = e / 160, t = e - nb * 160;
    ldw[e] = (t < H_) ? (lr[(size_t)row_i * 304 + t] + dWg[nb * H_ + t]) : 0.f;
  }
  // stage Wo^T bf16 [16][160] (rows l>=12 and cols t>=150 zero)
  for (int e = tid; e < 16 * 160; e += 256){
    int l = e / 160, t = e - l * 160;
    float w = (l < L_ && t < H_) ? Wo[t * L_ + l] : 0.f;
    wo_s[l][t] = f2bf(w);
  }
  // zero h tail cols 150..159 (persist across chunks; build writes only t<150)
  for (int e = tid; e < 64 * 5; e += 256){
    int row = e / 5, w5 = e - row * 5;
    *(unsigned*)&h_s[row][150 + w5 * 2] = 0u;
  }
  // buckets for this j-half, once per block
  if (tid < 192) bks[tid] = bucketf(span_begin[b * K_ + jhalf * 192 + tid] - se);
  int wave = tid >> 6, lane = tid & 63;
  int q = lane >> 4, mr = lane & 15;
  int jj = tid >> 2, tq = tid & 3;
  float bov = (mr < L_) ? bo[mr] : 0.f;
  __syncthreads();
#pragma unroll
  for (int c = 0; c < 3; ++c){
    int j0 = jhalf * 192 + c * 64;
    // build h bf16 for 64 j rows: 4 threads/row, 19 float2 pairs each (last predicated)
    {
      int bk = bks[c * 64 + jj];
      const float2* rr = (const float2*)(lr + (size_t)(b * K_ + j0 + jj) * 304 + 150);
      const float2* lw = (const float2*)(ldw + bk * 160);
      u16* hrow = &h_s[jj][0];
      int p = tq * 19;
#pragma unroll
      for (int s = 0; s < 19; ++s, ++p){
        if (p < 75){
          float2 rv = rr[p];
          float2 lv = lw[p];
          u16 h0 = f2bf(fmaxf(lv.x + rv.x, 0.f));
          u16 h1 = f2bf(fmaxf(lv.y + rv.y, 0.f));
          *(unsigned*)&hrow[p * 2] = (unsigned)h0 | ((unsigned)h1 << 16);
        }
      }
    }
    __syncthreads();
    // MFMA: wave handles 16 j rows x 16 l cols (12 valid), K=160
    f32x4 acc = {0.f, 0.f, 0.f, 0.f};
#pragma unroll
    for (int ks = 0; ks < 160; ks += 32){
      bf16x8 a = *(const bf16x8*)&h_s[wave * 16 + mr][ks + q * 8];
      bf16x8 w = *(const bf16x8*)&wo_s[mr][ks + q * 8];
      acc = __builtin_amdgcn_mfma_f32_16x16x32_bf16(a, w, acc, 0, 0, 0);
    }
    if (mr < L_){
#pragma unroll
      for (int r = 0; r < 4; ++r){
        int j = j0 + wave * 16 + q * 4 + r;
        size_t addr = ((size_t)row_i * K_ + j) * L_ + mr;
        float v = acc[r] + bov;
        if (accumulate) v += scores[addr];
        scores[addr] = v;
      }
    }
    __syncthreads();
  }
}

// ---------------- probs = sigmoid(max_l scores) * mask ; rowsum ; bf16 copy
__global__ __launch_bounds__(384)
void probs_kernel(const float* __restrict__ scores, const float* __restrict__ mask,
                  float* __restrict__ probs, u16* __restrict__ pbf,
                  float* __restrict__ rowsum){
  int i = blockIdx.x, b = blockIdx.y, j = threadIdx.x;
  size_t base = (size_t)(b * K_ + i) * K_ + j;
  const float* srow = scores + base * 12;
  float m = srow[0];
#pragma unroll
  for (int l = 1; l < 12; ++l) m = fmaxf(m, srow[l]);
  float p = mask[base] / (1.f + expf(-m));
  probs[base] = p;
  pbf[base] = f2bf(p);
  __shared__ float red[6];
  float s = p;
  for (int o = 32; o > 0; o >>= 1) s += __shfl_down(s, o, 64);
  if ((j & 63) == 0) red[j >> 6] = s;
  __syncthreads();
  if (j == 0){
    float tot = 0.f;
    for (int w = 0; w < 6; ++w) tot += red[w];
    rowsum[b * K_ + i] = tot;
  }
}

// ---------------- PTbf[b,j,i] = bf16(probs[b,i,j])
__global__ void transP_bf(const float* __restrict__ probs, u16* __restrict__ PTbf){
  __shared__ float t[32][33];
  int b = blockIdx.z;
  int bx = blockIdx.x * 32, by = blockIdx.y * 32;
  const float* P = probs + (size_t)b * K_ * K_;
  u16* PT = PTbf + (size_t)b * K_ * K_;
  int tx = threadIdx.x, ty = threadIdx.y;
  for (int i = 0; i < 32; i += 8) t[ty + i][tx] = P[(size_t)(by + ty + i) * K_ + bx + tx];
  __syncthreads();
  for (int i = 0; i < 32; i += 8) PT[(size_t)(bx + ty + i) * K_ + by + tx] = f2bf(t[tx][ty + i]);
}

// ---------------- colsum[b,j] = sum_i probs[b,i,j]  (grid (B,6), partial + atomic)
__global__ __launch_bounds__(384)
void colsum_kernel(const float* __restrict__ probs, float* __restrict__ colsum){
  int b = blockIdx.x, part = blockIdx.y, j = threadIdx.x;
  float s = 0.f;
  for (int i = part * 64; i < part * 64 + 64; ++i) s += probs[((size_t)b * K_ + i) * K_ + j];
  atomicAdd(&colsum[b * K_ + j], s);
}

// ---------------- float4 copy
__global__ void copy_f4(const float4* __restrict__ src, float4* __restrict__ dst, int n){
  int g = blockIdx.x * 256 + threadIdx.x;
  if (g < n) dst[g] = src[g];
}

// ---------------- overwrite_spans scatter (numpy last-wins for duplicate indices)
__global__ void scatter_kernel(const float* __restrict__ u, const int* __restrict__ prune,
                               const int* __restrict__ span_len, float* __restrict__ outA){
  int blk = blockIdx.x;
  int b = blk / K_, k = blk - b * K_;
  int idx = prune[b * K_ + k];
  bool valid = k < span_len[b];
  bool winner = (k == K_ - 1) || (prune[b * K_ + k + 1] != idx);
  if (!(valid && winner)) return;
  const float4* src = (const float4*)(u + ((size_t)b * K_ + k) * D_);
  float4* dst = (float4*)(outA + ((size_t)b * N_ + idx) * D_);
  for (int t = threadIdx.x; t < D_ / 4; t += blockDim.x) dst[t] = src[t];
}

extern "C" void kernel_launch(void* const* d_in, const int* in_sizes, int n_in,
                              void* d_out, int out_size, void* d_ws, size_t ws_size,
                              hipStream_t stream){
  const float* span_vecs = (const float*)d_in[0];
  const float* all_span  = (const float*)d_in[1];
  const int*   span_begin = (const int*)d_in[2];
  const int*   span_end   = (const int*)d_in[3];
  const float* mask       = (const float*)d_in[4];
  const int*   prune      = (const int*)d_in[5];
  const int*   span_len   = (const int*)d_in[6];
  const float* Wl  = (const float*)d_in[8];
  const float* bl  = (const float*)d_in[9];
  const float* Wr  = (const float*)d_in[10];
  const float* br  = (const float*)d_in[11];
  const float* dist_emb = (const float*)d_in[12];
  const float* Wd  = (const float*)d_in[13];
  const float* bd  = (const float*)d_in[14];
  const float* Wo  = (const float*)d_in[15];
  const float* bo  = (const float*)d_in[16];
  const float* Wff1 = (const float*)d_in[17];
  const float* Wff2 = (const float*)d_in[18];
  const float* Wg  = (const float*)d_in[19];
  const float* bg  = (const float*)d_in[20];

  float* outA = (float*)d_out;                       // (B,N,D)
  float* outU = outA + (size_t)B_ * N_ * D_;         // (B,K,D)
  float* outS = outU + (size_t)B_ * K_ * D_;         // (B,K,K,L)

  char* base = (char*)d_ws;
  size_t off = 0;
  auto alloc = [&](size_t bytes) -> void* {
    void* p = base + off;
    off = (off + bytes + 255) & ~((size_t)255);
    return p;
  };
  u16* WlrT  = (u16*)alloc((size_t)300 * 1024 * sizeof(u16));
  u16* Wff1T = (u16*)alloc((size_t)1024 * 3072 * sizeof(u16));
  u16* Wff2T = (u16*)alloc((size_t)1024 * 1024 * sizeof(u16));
  u16* WgT   = (u16*)alloc((size_t)1024 * 2048 * sizeof(u16));
  float* dWg = (float*)alloc(NB_ * H_ * sizeof(float));
  float* blr = (float*)alloc(300 * sizeof(float));
  float* lr  = (float*)alloc((size_t)B_ * K_ * 304 * sizeof(float));
  float* probs  = (float*)alloc((size_t)B_ * K_ * K_ * sizeof(float));
  u16* pbf   = (u16*)alloc((size_t)B_ * K_ * K_ * sizeof(u16));
  u16* pTbf  = (u16*)alloc((size_t)B_ * K_ * K_ * sizeof(u16));
  u16* uTbf  = (u16*)alloc((size_t)B_ * D_ * K_ * sizeof(u16));
  float* rowsum = (float*)alloc(B_ * K_ * sizeof(float));
  float* colsum = (float*)alloc(B_ * K_ * sizeof(float));
  u16* ubf0 = (u16*)alloc((size_t)B_ * K_ * D_ * sizeof(u16));
  u16* ubf1 = (u16*)alloc((size_t)B_ * K_ * D_ * sizeof(u16));
  u16* c1bf = (u16*)alloc((size_t)B_ * K_ * D_ * sizeof(u16));
  u16* c2bf = (u16*)alloc((size_t)B_ * K_ * D_ * sizeof(u16));
  u16* tbf  = (u16*)alloc((size_t)B_ * K_ * D_ * sizeof(u16));
  u16* ctxtbf = (u16*)alloc((size_t)B_ * K_ * D_ * sizeof(u16));
  float* uA = (float*)alloc((size_t)B_ * K_ * D_ * sizeof(float));
  float* accF = (float*)alloc((size_t)B_ * K_ * D_ * sizeof(float));  // split-K fp32 accum
  u16* ubf[2] = {ubf0, ubf1};
  (void)ws_size; (void)in_sizes; (void)n_in; (void)out_size;

  dim3 tb(32, 8);
  transpose_f2bf<<<dim3(5, 32), tb, 0, stream>>>(Wl, WlrT, 1024, 150, 1024);
  transpose_f2bf<<<dim3(5, 32), tb, 0, stream>>>(Wr, WlrT + 150 * 1024, 1024, 150, 1024);
  transpose_f2bf<<<dim3(32, 96), tb, 0, stream>>>(Wff1, Wff1T, 3072, 1024, 3072);
  transpose_f2bf<<<dim3(32, 32), tb, 0, stream>>>(Wff2, Wff2T, 1024, 1024, 1024);
  transpose_f2bf<<<dim3(32, 64), tb, 0, stream>>>(Wg, WgT, 2048, 1024, 2048);
  small_setup<<<1, 256, 0, stream>>>(dist_emb, Wd, bd, bl, br, dWg, blr);
  cvt_f32_bf16<<<768, 256, 0, stream>>>(span_vecs, ubf[0], B_ * K_ * D_);

  // lr = u0 @ [Wl|Wr] + [bl|br]   (split-K=8, 480 blocks, atomic accum into bias-filled lr)
  init_lr<<<912, 256, 0, stream>>>(blr, lr);
  gemm_part_atomic<<<dim3(12, 5, 8), 256, 0, stream>>>(ubf[0], nullptr, nullptr, WlrT,
                                                       300, 1024, 128, lr, 304);
  scorer_kernel<<<dim3(K_, 2, B_), 256, 0, stream>>>(lr, dWg, Wo, bo, span_begin, span_end, outS, 0);

  const float* ucurF = span_vecs;
  int cb = 0;
  float* unexts[2] = {uA, outU};   // it=1 writes u directly into d_out
  for (int it = 0; it < 2; ++it){
    probs_kernel<<<dim3(K_, B_), 384, 0, stream>>>(outS, mask, probs, pbf, rowsum);
    transP_bf<<<dim3(12, 12, B_), tb, 0, stream>>>(probs, pTbf);
    (void)hipMemsetAsync(colsum, 0, B_ * K_ * sizeof(float), stream);
    colsum_kernel<<<dim3(B_, 6), 384, 0, stream>>>(probs, colsum);
    transpose_bf<<<dim3(32, 12, B_), tb, 0, stream>>>(ubf[cb], uTbf);
    ctxt_mfma<<<dim3(6, 16, 2 * B_), 256, 0, stream>>>(pbf, pTbf, uTbf, rowsum, colsum,
                                                       c1bf, c2bf);
    // tbf = tanh(cat(u,c1,c2) @ Wff1)   K=3072, split-K=8 (1536 blocks)
    (void)hipMemsetAsync(accF, 0, (size_t)B_ * K_ * D_ * sizeof(float), stream);
    gemm_part_atomic<<<dim3(12, 16, 8), 256, 0, stream>>>(ubf[cb], c1bf, c2bf, Wff1T,
                                                          1024, 3072, 384, accF, 1024);
    gemm_epi<<<3072, 256, 0, stream>>>(accF, B_ * K_ * D_, nullptr, 1,
                                       nullptr, tbf, nullptr, nullptr);
    // ctxt = tbf @ Wff2                 K=1024, split-K=8
    (void)hipMemsetAsync(accF, 0, (size_t)B_ * K_ * D_ * sizeof(float), stream);
    gemm_part_atomic<<<dim3(12, 16, 8), 256, 0, stream>>>(tbf, nullptr, nullptr, Wff2T,
                                                          1024, 1024, 128, accF, 1024);
    gemm_epi<<<3072, 256, 0, stream>>>(accF, B_ * K_ * D_, nullptr, 2,
                                       nullptr, ctxtbf, nullptr, nullptr);
    // gate: g = sigmoid(cat(u,ctxt) @ Wg + bg); un = g*u + (1-g)*ctxt   K=2048, split-K=8
    (void)hipMemsetAsync(accF, 0, (size_t)B_ * K_ * D_ * sizeof(float), stream);
    gemm_part_atomic<<<dim3(12, 16, 8), 256, 0, stream>>>(ubf[cb], ctxtbf, nullptr, WgT,
                                                          1024, 2048, 256, accF, 1024);
    float* unext = unexts[it];
    gemm_epi<<<3072, 256, 0, stream>>>(accF, B_ * K_ * D_, bg, 3,
                                       unext, ubf[1 - cb], ucurF, ctxtbf);
    cb = 1 - cb;
    ucurF = unext;
    // lr for next scorer               K=1024, split-K=8
    init_lr<<<912, 256, 0, stream>>>(blr, lr);
    gemm_part_atomic<<<dim3(12, 5, 8), 256, 0, stream>>>(ubf[cb], nullptr, nullptr, WlrT,
                                                         300, 1024, 128, lr, 304);
    scorer_kernel<<<dim3(K_, 2, B_), 256, 0, stream>>>(lr, dWg, Wo, bo, span_begin, span_end, outS, 1);
  }

  copy_f4<<<8192, 256, 0, stream>>>((const float4*)all_span, (float4*)outA, (B_ * N_ * D_) / 4);
  // ucurF == outU after it=1 — no final u copy needed
  scatter_kernel<<<B_ * K_, 256, 0, stream>>>(ucurF, prune, span_len, outA);
}

// Round 5
// 559.133 us; speedup vs baseline: 1.0307x; 1.0307x over previous
//
#include <hip/hip_runtime.h>
#include <cmath>

#define B_ 2
#define K_ 384
#define N_ 4096
#define D_ 1024
#define H_ 150
#define L_ 12
#define NB_ 10

typedef unsigned short u16;
typedef __bf16 bf16x8 __attribute__((ext_vector_type(8)));
typedef float f32x4 __attribute__((ext_vector_type(4)));

__device__ __forceinline__ u16 f2bf(float f){
  unsigned u = __builtin_bit_cast(unsigned, f);
  unsigned r = (u + 0x7FFFu + ((u >> 16) & 1u)) >> 16;
  return (u16)r;
}
__device__ __forceinline__ float bf2f(u16 h){
  unsigned u = ((unsigned)h) << 16;
  return __builtin_bit_cast(float, u);
}
__device__ __forceinline__ int bucketf(int d){
  int da = d < 0 ? -d : d;
  if (da <= 4) return da;
  int lg = 31 - __clz(da);
  int v = lg + 3;
  return v > NB_ - 1 ? NB_ - 1 : v;
}

// ---------------- transpose fp32 (Kd x Nd) -> bf16 (Nd x Kd), out row stride = ostride
__global__ void transpose_f2bf(const float* __restrict__ in, u16* __restrict__ out,
                               int Kd, int Nd, int ostride){
  __shared__ float t[32][33];
  int bx = blockIdx.x * 32, by = blockIdx.y * 32;
  int tx = threadIdx.x, ty = threadIdx.y;
  for (int i = 0; i < 32; i += 8){
    int k = by + ty + i, n = bx + tx;
    t[ty + i][tx] = (k < Kd && n < Nd) ? in[(size_t)k * Nd + n] : 0.f;
  }
  __syncthreads();
  for (int i = 0; i < 32; i += 8){
    int n = bx + ty + i, k = by + tx;
    if (n < Nd && k < Kd) out[(size_t)n * ostride + k] = f2bf(t[tx][ty + i]);
  }
}

// ---------------- transpose bf16 (K_ x D_) -> (D_ x K_) per batch
__global__ void transpose_bf(const u16* __restrict__ in, u16* __restrict__ out){
  __shared__ u16 t[32][34];
  int b = blockIdx.z;
  const u16* I = in + (size_t)b * K_ * D_;
  u16* O = out + (size_t)b * D_ * K_;
  int bx = blockIdx.x * 32, by = blockIdx.y * 32;  // bx: d, by: k
  int tx = threadIdx.x, ty = threadIdx.y;
  for (int i = 0; i < 32; i += 8) t[ty + i][tx] = I[(size_t)(by + ty + i) * D_ + bx + tx];
  __syncthreads();
  for (int i = 0; i < 32; i += 8) O[(size_t)(bx + ty + i) * K_ + by + tx] = t[tx][ty + i];
}

// ---------------- small setup: dW[10][150] = dist_emb @ Wd + bd ; blr = [bl | br]
__global__ void small_setup(const float* __restrict__ dist_emb, const float* __restrict__ Wd,
                            const float* __restrict__ bd, const float* __restrict__ bl,
                            const float* __restrict__ br, float* __restrict__ dWg,
                            float* __restrict__ blr){
  int tid = threadIdx.x;
  for (int idx = tid; idx < NB_ * H_; idx += 256){
    int nb = idx / H_, h = idx - nb * H_;
    float s = bd[h];
    for (int dd = 0; dd < 20; ++dd) s += dist_emb[nb * 20 + dd] * Wd[dd * H_ + h];
    dWg[idx] = s;
  }
  for (int idx = tid; idx < H_; idx += 256){
    blr[idx] = bl[idx];
    blr[H_ + idx] = br[idx];
  }
}

// ---------------- fp32 -> bf16 elementwise (n divisible by 4)
__global__ void cvt_f32_bf16(const float* __restrict__ in, u16* __restrict__ out, int n){
  int idx = (blockIdx.x * 256 + threadIdx.x) * 4;
  if (idx < n){
    float4 v = *(const float4*)(in + idx);
    ushort4 o;
    o.x = f2bf(v.x); o.y = f2bf(v.y); o.z = f2bf(v.z); o.w = f2bf(v.w);
    *(ushort4*)(out + idx) = o;
  }
}

// ---------------- init lr with broadcast bias (cols 0..299 = blr, pad = 0)
__global__ void init_lr(const float* __restrict__ blr, float* __restrict__ lr){
  int idx = blockIdx.x * 256 + threadIdx.x;
  if (idx >= (B_ * K_) * 304) return;
  int col = idx % 304;
  lr[idx] = (col < 300) ? blr[col] : 0.f;
}

// ---------------- bf16 MFMA GEMM, split-K with atomic fp32 accumulation
__global__ __launch_bounds__(256)
void gemm_part_atomic(const u16* __restrict__ A0, const u16* __restrict__ A1,
                      const u16* __restrict__ A2, const u16* __restrict__ BT,
                      int Nn, int Ktot, int klen,
                      float* __restrict__ Out, int ldo){
  __shared__ u16 As[64][72];
  __shared__ u16 Bs[64][72];
  int tid = threadIdx.x;
  int m0 = blockIdx.x * 64, n0 = blockIdx.y * 64;
  int s = blockIdx.z;
  int kbeg = s * klen, kend = kbeg + klen;
  int wave = tid >> 6, lane = tid & 63;
  int wm = wave >> 1, wn = wave & 1;
  int q = lane >> 4, mr = lane & 15;
  f32x4 acc[2][2] = {{{0.f,0.f,0.f,0.f},{0.f,0.f,0.f,0.f}},{{0.f,0.f,0.f,0.f},{0.f,0.f,0.f,0.f}}};
  const u16* Achunks[3] = {A0, A1, A2};
  for (int k0 = kbeg; k0 < kend; k0 += 64){
    const u16* Ap = Achunks[k0 >> 10] + (k0 & 1023);
    for (int c = tid; c < 512; c += 256){
      int row = c >> 3, c8 = c & 7;
      *(uint4*)&As[row][c8 * 8] = *(const uint4*)&Ap[(size_t)(m0 + row) * 1024 + c8 * 8];
    }
    for (int c = tid; c < 512; c += 256){
      int row = c >> 3, c8 = c & 7;
      int n = n0 + row;
      uint4 v; v.x = 0; v.y = 0; v.z = 0; v.w = 0;
      if (n < Nn) v = *(const uint4*)&BT[(size_t)n * Ktot + k0 + c8 * 8];
      *(uint4*)&Bs[row][c8 * 8] = v;
    }
    __syncthreads();
#pragma unroll
    for (int ks = 0; ks < 64; ks += 32){
      bf16x8 a0 = *(const bf16x8*)&As[wm * 32 + mr][ks + q * 8];
      bf16x8 a1 = *(const bf16x8*)&As[wm * 32 + 16 + mr][ks + q * 8];
      bf16x8 b0 = *(const bf16x8*)&Bs[wn * 32 + mr][ks + q * 8];
      bf16x8 b1 = *(const bf16x8*)&Bs[wn * 32 + 16 + mr][ks + q * 8];
      acc[0][0] = __builtin_amdgcn_mfma_f32_16x16x32_bf16(a0, b0, acc[0][0], 0, 0, 0);
      acc[0][1] = __builtin_amdgcn_mfma_f32_16x16x32_bf16(a0, b1, acc[0][1], 0, 0, 0);
      acc[1][0] = __builtin_amdgcn_mfma_f32_16x16x32_bf16(a1, b0, acc[1][0], 0, 0, 0);
      acc[1][1] = __builtin_amdgcn_mfma_f32_16x16x32_bf16(a1, b1, acc[1][1], 0, 0, 0);
    }
    __syncthreads();
  }
#pragma unroll
  for (int mt = 0; mt < 2; ++mt){
#pragma unroll
    for (int nt = 0; nt < 2; ++nt){
      int col = n0 + wn * 32 + nt * 16 + mr;
      if (col >= Nn) continue;
#pragma unroll
      for (int r = 0; r < 4; ++r){
        int row = m0 + wm * 32 + mt * 16 + q * 4 + r;
        atomicAdd(&Out[(size_t)row * ldo + col], acc[mt][nt][r]);
      }
    }
  }
}

// ---------------- epilogue over fp32 accum (ld = 1024)
// mode 1: outH = bf16(tanh(acc))
// mode 2: outH = bf16(acc)
// mode 3: g = sigmoid(acc + bias[col]); un = g*uin + (1-g)*ctxtin; outF fp32, outH bf16
__global__ __launch_bounds__(256)
void gemm_epi(const float* __restrict__ accF, int n,
              const float* __restrict__ bias, int mode,
              float* __restrict__ outF, u16* __restrict__ outH,
              const float* __restrict__ uin, const u16* __restrict__ ctxtin){
  int idx = blockIdx.x * 256 + threadIdx.x;
  if (idx >= n) return;
  float ssum = accF[idx];
  if (mode == 1){
    outH[idx] = f2bf(tanhf(ssum));
  } else if (mode == 2){
    outH[idx] = f2bf(ssum);
  } else {
    int col = idx & 1023;
    float g = 1.f / (1.f + expf(-(ssum + bias[col])));
    float uo = uin[idx];
    float ct = bf2f(ctxtin[idx]);
    float un = ct + g * (uo - ct);
    outF[idx] = un;
    outH[idx] = f2bf(un);
  }
}

// ---------------- ctxt via MFMA: c{1,2}[b,i,d] = (P{,T}[b] @ u[b])[i,d] / (sum+eps)
__global__ __launch_bounds__(256)
void ctxt_mfma(const u16* __restrict__ Pbf, const u16* __restrict__ PTbf,
               const u16* __restrict__ uT, const float* __restrict__ rowsum,
               const float* __restrict__ colsum, u16* __restrict__ c1,
               u16* __restrict__ c2){
  __shared__ u16 As[64][72];
  __shared__ u16 Bs[64][72];
  int z = blockIdx.z, b = z >> 1, which = z & 1;
  const u16* A = (which ? PTbf : Pbf) + (size_t)b * K_ * K_;
  const u16* BT = uT + (size_t)b * D_ * K_;
  const float* sums = (which ? colsum : rowsum) + b * K_;
  u16* out = which ? c2 : c1;
  int tid = threadIdx.x;
  int m0 = blockIdx.x * 64, n0 = blockIdx.y * 64;
  int wave = tid >> 6, lane = tid & 63;
  int wm = wave >> 1, wn = wave & 1;
  int q = lane >> 4, mr = lane & 15;
  f32x4 acc[2][2] = {{{0.f,0.f,0.f,0.f},{0.f,0.f,0.f,0.f}},{{0.f,0.f,0.f,0.f},{0.f,0.f,0.f,0.f}}};
  for (int k0 = 0; k0 < K_; k0 += 64){
    for (int c = tid; c < 512; c += 256){
      int row = c >> 3, c8 = c & 7;
      *(uint4*)&As[row][c8 * 8] = *(const uint4*)&A[(size_t)(m0 + row) * K_ + k0 + c8 * 8];
    }
    for (int c = tid; c < 512; c += 256){
      int row = c >> 3, c8 = c & 7;
      *(uint4*)&Bs[row][c8 * 8] = *(const uint4*)&BT[(size_t)(n0 + row) * K_ + k0 + c8 * 8];
    }
    __syncthreads();
#pragma unroll
    for (int ks = 0; ks < 64; ks += 32){
      bf16x8 a0 = *(const bf16x8*)&As[wm * 32 + mr][ks + q * 8];
      bf16x8 a1 = *(const bf16x8*)&As[wm * 32 + 16 + mr][ks + q * 8];
      bf16x8 b0 = *(const bf16x8*)&Bs[wn * 32 + mr][ks + q * 8];
      bf16x8 b1 = *(const bf16x8*)&Bs[wn * 32 + 16 + mr][ks + q * 8];
      acc[0][0] = __builtin_amdgcn_mfma_f32_16x16x32_bf16(a0, b0, acc[0][0], 0, 0, 0);
      acc[0][1] = __builtin_amdgcn_mfma_f32_16x16x32_bf16(a0, b1, acc[0][1], 0, 0, 0);
      acc[1][0] = __builtin_amdgcn_mfma_f32_16x16x32_bf16(a1, b0, acc[1][0], 0, 0, 0);
      acc[1][1] = __builtin_amdgcn_mfma_f32_16x16x32_bf16(a1, b1, acc[1][1], 0, 0, 0);
    }
    __syncthreads();
  }
#pragma unroll
  for (int mt = 0; mt < 2; ++mt){
#pragma unroll
    for (int nt = 0; nt < 2; ++nt){
      int col = n0 + wn * 32 + nt * 16 + mr;
#pragma unroll
      for (int r = 0; r < 4; ++r){
        int row = m0 + wm * 32 + mt * 16 + q * 4 + r;
        float w = 1.f / (sums[row] + 1e-7f);
        out[((size_t)(b * K_ + row)) * D_ + col] = f2bf(acc[mt][nt][r] * w);
      }
    }
  }
}

// ---------------- scorer (MFMA, v3 wave-autonomous):
// scores[b,i,j,l] (+)= relu(l_i + r_j + dW[bk]) @ Wo + bo
// grid (K, 3, B): each block covers 128 j-rows; each wave owns 32 rows (2 passes of 16),
// builds its private LDS tile, runs its own MFMA chain, writes — no per-chunk barriers.
// Wo^T fragments live in 20 VGPRs/lane. Single __syncthreads after shared ldw stage.
__global__ __launch_bounds__(256)
void scorer_kernel(const float* __restrict__ lr, const float* __restrict__ dWg,
                   const float* __restrict__ Wo, const float* __restrict__ bo,
                   const int* __restrict__ span_begin, const int* __restrict__ span_end,
                   float* __restrict__ scores, int accumulate){
  __shared__ float ldw[NB_ * 160];
  __shared__ u16 h_s[4][16][168];
  int i = blockIdx.x, jblk = blockIdx.y, b = blockIdx.z;
  int tid = threadIdx.x;
  int row_i = b * K_ + i;
  int se = span_end[row_i];
  // stage ldw = l_i + dW (zero pad t>=150), block-cooperative
  for (int e = tid; e < NB_ * 160; e += 256){
    int nb = e / 160, t = e - nb * 160;
    ldw[e] = (t < H_) ? (lr[(size_t)row_i * 304 + t] + dWg[nb * H_ + t]) : 0.f;
  }
  int wave = tid >> 6, lane = tid & 63;
  int q = lane >> 4, mr = lane & 15;
  // Wo^T fragments in registers: wo_frag[kk][e] = Wo^T[mr][kk*32 + q*8 + e]
  bf16x8 wo_frag[5];
#pragma unroll
  for (int kk = 0; kk < 5; ++kk){
    u16 tmp[8];
#pragma unroll
    for (int e = 0; e < 8; ++e){
      int t = kk * 32 + q * 8 + e;
      float w = (mr < L_ && t < H_) ? Wo[t * L_ + mr] : 0.f;
      tmp[e] = f2bf(w);
    }
    wo_frag[kk] = *(const bf16x8*)tmp;
  }
  // zero this wave's h tail cols [150,160)
  for (int e = lane; e < 16 * 5; e += 64){
    int row = e / 5, w5 = e - row * 5;
    *(unsigned*)&h_s[wave][row][150 + w5 * 2] = 0u;
  }
  float bov = (mr < L_) ? bo[mr] : 0.f;
  int rt = lane >> 2, tq = lane & 3;   // build mapping: 4 lanes per row
  __syncthreads();
#pragma unroll
  for (int p = 0; p < 2; ++p){
    int j0w = jblk * 128 + wave * 32 + p * 16;
    // build h bf16 for this wave's 16 rows
    {
      int j = j0w + rt;
      int bk = bucketf(span_begin[b * K_ + j] - se);
      const float2* rr = (const float2*)(lr + (size_t)(b * K_ + j) * 304 + 150);
      const float2* lw = (const float2*)(ldw + bk * 160);
      u16* hrow = &h_s[wave][rt][0];
      int pp = tq * 19;
#pragma unroll
      for (int s = 0; s < 19; ++s, ++pp){
        if (pp < 75){
          float2 rv = rr[pp];
          float2 lv = lw[pp];
          u16 h0 = f2bf(fmaxf(lv.x + rv.x, 0.f));
          u16 h1 = f2bf(fmaxf(lv.y + rv.y, 0.f));
          *(unsigned*)&hrow[pp * 2] = (unsigned)h0 | ((unsigned)h1 << 16);
        }
      }
    }
    // MFMA: 16 j rows x 16 l cols (12 valid), K=160 (intra-wave LDS dep only)
    f32x4 acc = {0.f, 0.f, 0.f, 0.f};
#pragma unroll
    for (int kk = 0; kk < 5; ++kk){
      bf16x8 a = *(const bf16x8*)&h_s[wave][mr][kk * 32 + q * 8];
      acc = __builtin_amdgcn_mfma_f32_16x16x32_bf16(a, wo_frag[kk], acc, 0, 0, 0);
    }
    if (mr < L_){
#pragma unroll
      for (int r = 0; r < 4; ++r){
        int j = j0w + q * 4 + r;
        size_t addr = ((size_t)row_i * K_ + j) * L_ + mr;
        float v = acc[r] + bov;
        if (accumulate) v += scores[addr];
        scores[addr] = v;
      }
    }
  }
}

// ---------------- probs = sigmoid(max_l scores) * mask ; rowsum ; pbf ; pTbf ; colsum
__global__ __launch_bounds__(384)
void probs_kernel(const float* __restrict__ scores, const float* __restrict__ mask,
                  float* __restrict__ probs, u16* __restrict__ pbf,
                  u16* __restrict__ pTbf, float* __restrict__ rowsum,
                  float* __restrict__ colsum){
  int i = blockIdx.x, b = blockIdx.y, j = threadIdx.x;
  size_t base = (size_t)(b * K_ + i) * K_ + j;
  const float* srow = scores + base * 12;
  float m = srow[0];
#pragma unroll
  for (int l = 1; l < 12; ++l) m = fmaxf(m, srow[l]);
  float p = mask[base] / (1.f + expf(-m));
  probs[base] = p;
  u16 ph = f2bf(p);
  pbf[base] = ph;
  pTbf[((size_t)b * K_ + j) * K_ + i] = ph;                 // fused transP
  atomicAdd(&colsum[b * K_ + j], p);                        // fused colsum
  __shared__ float red[6];
  float s = p;
  for (int o = 32; o > 0; o >>= 1) s += __shfl_down(s, o, 64);
  if ((j & 63) == 0) red[j >> 6] = s;
  __syncthreads();
  if (j == 0){
    float tot = 0.f;
    for (int w = 0; w < 6; ++w) tot += red[w];
    rowsum[b * K_ + i] = tot;
  }
}

// ---------------- float4 copy
__global__ void copy_f4(const float4* __restrict__ src, float4* __restrict__ dst, int n){
  int g = blockIdx.x * 256 + threadIdx.x;
  if (g < n) dst[g] = src[g];
}

// ---------------- overwrite_spans scatter (numpy last-wins for duplicate indices)
__global__ void scatter_kernel(const float* __restrict__ u, const int* __restrict__ prune,
                               const int* __restrict__ span_len, float* __restrict__ outA){
  int blk = blockIdx.x;
  int b = blk / K_, k = blk - b * K_;
  int idx = prune[b * K_ + k];
  bool valid = k < span_len[b];
  bool winner = (k == K_ - 1) || (prune[b * K_ + k + 1] != idx);
  if (!(valid && winner)) return;
  const float4* src = (const float4*)(u + ((size_t)b * K_ + k) * D_);
  float4* dst = (float4*)(outA + ((size_t)b * N_ + idx) * D_);
  for (int t = threadIdx.x; t < D_ / 4; t += blockDim.x) dst[t] = src[t];
}

extern "C" void kernel_launch(void* const* d_in, const int* in_sizes, int n_in,
                              void* d_out, int out_size, void* d_ws, size_t ws_size,
                              hipStream_t stream){
  const float* span_vecs = (const float*)d_in[0];
  const float* all_span  = (const float*)d_in[1];
  const int*   span_begin = (const int*)d_in[2];
  const int*   span_end   = (const int*)d_in[3];
  const float* mask       = (const float*)d_in[4];
  const int*   prune      = (const int*)d_in[5];
  const int*   span_len   = (const int*)d_in[6];
  const float* Wl  = (const float*)d_in[8];
  const float* bl  = (const float*)d_in[9];
  const float* Wr  = (const float*)d_in[10];
  const float* br  = (const float*)d_in[11];
  const float* dist_emb = (const float*)d_in[12];
  const float* Wd  = (const float*)d_in[13];
  const float* bd  = (const float*)d_in[14];
  const float* Wo  = (const float*)d_in[15];
  const float* bo  = (const float*)d_in[16];
  const float* Wff1 = (const float*)d_in[17];
  const float* Wff2 = (const float*)d_in[18];
  const float* Wg  = (const float*)d_in[19];
  const float* bg  = (const float*)d_in[20];

  float* outA = (float*)d_out;                       // (B,N,D)
  float* outU = outA + (size_t)B_ * N_ * D_;         // (B,K,D)
  float* outS = outU + (size_t)B_ * K_ * D_;         // (B,K,K,L)

  char* base = (char*)d_ws;
  size_t off = 0;
  auto alloc = [&](size_t bytes) -> void* {
    void* p = base + off;
    off = (off + bytes + 255) & ~((size_t)255);
    return p;
  };
  u16* WlrT  = (u16*)alloc((size_t)300 * 1024 * sizeof(u16));
  u16* Wff1T = (u16*)alloc((size_t)1024 * 3072 * sizeof(u16));
  u16* Wff2T = (u16*)alloc((size_t)1024 * 1024 * sizeof(u16));
  u16* WgT   = (u16*)alloc((size_t)1024 * 2048 * sizeof(u16));
  float* dWg = (float*)alloc(NB_ * H_ * sizeof(float));
  float* blr = (float*)alloc(300 * sizeof(float));
  float* lr  = (float*)alloc((size_t)B_ * K_ * 304 * sizeof(float));
  float* probs  = (float*)alloc((size_t)B_ * K_ * K_ * sizeof(float));
  u16* pbf   = (u16*)alloc((size_t)B_ * K_ * K_ * sizeof(u16));
  u16* pTbf  = (u16*)alloc((size_t)B_ * K_ * K_ * sizeof(u16));
  u16* uTbf  = (u16*)alloc((size_t)B_ * D_ * K_ * sizeof(u16));
  float* rowsum = (float*)alloc(B_ * K_ * sizeof(float));
  float* colsum = (float*)alloc(B_ * K_ * sizeof(float));
  u16* ubf0 = (u16*)alloc((size_t)B_ * K_ * D_ * sizeof(u16));
  u16* ubf1 = (u16*)alloc((size_t)B_ * K_ * D_ * sizeof(u16));
  u16* c1bf = (u16*)alloc((size_t)B_ * K_ * D_ * sizeof(u16));
  u16* c2bf = (u16*)alloc((size_t)B_ * K_ * D_ * sizeof(u16));
  u16* tbf  = (u16*)alloc((size_t)B_ * K_ * D_ * sizeof(u16));
  u16* ctxtbf = (u16*)alloc((size_t)B_ * K_ * D_ * sizeof(u16));
  float* uA = (float*)alloc((size_t)B_ * K_ * D_ * sizeof(float));
  float* accF = (float*)alloc((size_t)B_ * K_ * D_ * sizeof(float));  // split-K fp32 accum
  u16* ubf[2] = {ubf0, ubf1};
  (void)ws_size; (void)in_sizes; (void)n_in; (void)out_size;

  dim3 tb(32, 8);
  transpose_f2bf<<<dim3(5, 32), tb, 0, stream>>>(Wl, WlrT, 1024, 150, 1024);
  transpose_f2bf<<<dim3(5, 32), tb, 0, stream>>>(Wr, WlrT + 150 * 1024, 1024, 150, 1024);
  transpose_f2bf<<<dim3(32, 96), tb, 0, stream>>>(Wff1, Wff1T, 3072, 1024, 3072);
  transpose_f2bf<<<dim3(32, 32), tb, 0, stream>>>(Wff2, Wff2T, 1024, 1024, 1024);
  transpose_f2bf<<<dim3(32, 64), tb, 0, stream>>>(Wg, WgT, 2048, 1024, 2048);
  small_setup<<<1, 256, 0, stream>>>(dist_emb, Wd, bd, bl, br, dWg, blr);
  cvt_f32_bf16<<<768, 256, 0, stream>>>(span_vecs, ubf[0], B_ * K_ * D_);

  // lr = u0 @ [Wl|Wr] + [bl|br]   (split-K=8, 480 blocks, atomic accum into bias-filled lr)
  init_lr<<<912, 256, 0, stream>>>(blr, lr);
  gemm_part_atomic<<<dim3(12, 5, 8), 256, 0, stream>>>(ubf[0], nullptr, nullptr, WlrT,
                                                       300, 1024, 128, lr, 304);
  scorer_kernel<<<dim3(K_, 3, B_), 256, 0, stream>>>(lr, dWg, Wo, bo, span_begin, span_end, outS, 0);

  const float* ucurF = span_vecs;
  int cb = 0;
  float* unexts[2] = {uA, outU};   // it=1 writes u directly into d_out
  for (int it = 0; it < 2; ++it){
    (void)hipMemsetAsync(colsum, 0, B_ * K_ * sizeof(float), stream);
    probs_kernel<<<dim3(K_, B_), 384, 0, stream>>>(outS, mask, probs, pbf, pTbf, rowsum, colsum);
    transpose_bf<<<dim3(32, 12, B_), tb, 0, stream>>>(ubf[cb], uTbf);
    ctxt_mfma<<<dim3(6, 16, 2 * B_), 256, 0, stream>>>(pbf, pTbf, uTbf, rowsum, colsum,
                                                       c1bf, c2bf);
    // tbf = tanh(cat(u,c1,c2) @ Wff1)   K=3072, split-K=4 (768 blocks)
    (void)hipMemsetAsync(accF, 0, (size_t)B_ * K_ * D_ * sizeof(float), stream);
    gemm_part_atomic<<<dim3(12, 16, 4), 256, 0, stream>>>(ubf[cb], c1bf, c2bf, Wff1T,
                                                          1024, 3072, 768, accF, 1024);
    gemm_epi<<<3072, 256, 0, stream>>>(accF, B_ * K_ * D_, nullptr, 1,
                                       nullptr, tbf, nullptr, nullptr);
    // ctxt = tbf @ Wff2                 K=1024, split-K=4
    (void)hipMemsetAsync(accF, 0, (size_t)B_ * K_ * D_ * sizeof(float), stream);
    gemm_part_atomic<<<dim3(12, 16, 4), 256, 0, stream>>>(tbf, nullptr, nullptr, Wff2T,
                                                          1024, 1024, 256, accF, 1024);
    gemm_epi<<<3072, 256, 0, stream>>>(accF, B_ * K_ * D_, nullptr, 2,
                                       nullptr, ctxtbf, nullptr, nullptr);
    // gate: g = sigmoid(cat(u,ctxt) @ Wg + bg); un = g*u + (1-g)*ctxt   K=2048, split-K=4
    (void)hipMemsetAsync(accF, 0, (size_t)B_ * K_ * D_ * sizeof(float), stream);
    gemm_part_atomic<<<dim3(12, 16, 4), 256, 0, stream>>>(ubf[cb], ctxtbf, nullptr, WgT,
                                                          1024, 2048, 512, accF, 1024);
    float* unext = unexts[it];
    gemm_epi<<<3072, 256, 0, stream>>>(accF, B_ * K_ * D_, bg, 3,
                                       unext, ubf[1 - cb], ucurF, ctxtbf);
    cb = 1 - cb;
    ucurF = unext;
    // lr for next scorer               K=1024, split-K=8
    init_lr<<<912, 256, 0, stream>>>(blr, lr);
    gemm_part_atomic<<<dim3(12, 5, 8), 256, 0, stream>>>(ubf[cb], nullptr, nullptr, WlrT,
                                                         300, 1024, 128, lr, 304);
    scorer_kernel<<<dim3(K_, 3, B_), 256, 0, stream>>>(lr, dWg, Wo, bo, span_begin, span_end, outS, 1);
  }

  copy_f4<<<8192, 256, 0, stream>>>((const float4*)all_span, (float4*)outA, (B_ * N_ * D_) / 4);
  // ucurF == outU after it=1 — no final u copy needed
  scatter_kernel<<<B_ * K_, 256, 0, stream>>>(ucurF, prune, span_len, outA);
}

// Round 6
// 537.477 us; speedup vs baseline: 1.0723x; 1.0403x over previous
//
#include <hip/hip_runtime.h>
#include <cmath>

#define B_ 2
#define K_ 384
#define N_ 4096
#define D_ 1024
#define H_ 150
#define L_ 12
#define NB_ 10

typedef unsigned short u16;
typedef __bf16 bf16x8 __attribute__((ext_vector_type(8)));
typedef float f32x4 __attribute__((ext_vector_type(4)));

__device__ __forceinline__ u16 f2bf(float f){
  unsigned u = __builtin_bit_cast(unsigned, f);
  unsigned r = (u + 0x7FFFu + ((u >> 16) & 1u)) >> 16;
  return (u16)r;
}
__device__ __forceinline__ float bf2f(u16 h){
  unsigned u = ((unsigned)h) << 16;
  return __builtin_bit_cast(float, u);
}
__device__ __forceinline__ int bucketf(int d){
  int da = d < 0 ? -d : d;
  if (da <= 4) return da;
  int lg = 31 - __clz(da);
  int v = lg + 3;
  return v > NB_ - 1 ? NB_ - 1 : v;
}

// ---------------- transpose fp32 (Kd x Nd) -> bf16 (Nd x Kd), out row stride = ostride
__global__ void transpose_f2bf(const float* __restrict__ in, u16* __restrict__ out,
                               int Kd, int Nd, int ostride){
  __shared__ float t[32][33];
  int bx = blockIdx.x * 32, by = blockIdx.y * 32;
  int tx = threadIdx.x, ty = threadIdx.y;
  for (int i = 0; i < 32; i += 8){
    int k = by + ty + i, n = bx + tx;
    t[ty + i][tx] = (k < Kd && n < Nd) ? in[(size_t)k * Nd + n] : 0.f;
  }
  __syncthreads();
  for (int i = 0; i < 32; i += 8){
    int n = bx + ty + i, k = by + tx;
    if (n < Nd && k < Kd) out[(size_t)n * ostride + k] = f2bf(t[tx][ty + i]);
  }
}

// ---------------- transpose bf16 (K_ x D_) -> (D_ x K_) per batch
__global__ void transpose_bf(const u16* __restrict__ in, u16* __restrict__ out){
  __shared__ u16 t[32][34];
  int b = blockIdx.z;
  const u16* I = in + (size_t)b * K_ * D_;
  u16* O = out + (size_t)b * D_ * K_;
  int bx = blockIdx.x * 32, by = blockIdx.y * 32;  // bx: d, by: k
  int tx = threadIdx.x, ty = threadIdx.y;
  for (int i = 0; i < 32; i += 8) t[ty + i][tx] = I[(size_t)(by + ty + i) * D_ + bx + tx];
  __syncthreads();
  for (int i = 0; i < 32; i += 8) O[(size_t)(bx + ty + i) * K_ + by + tx] = t[tx][ty + i];
}

// ---------------- small setup: dW[10][150] = dist_emb @ Wd + bd ; blr = [bl | br]
__global__ void small_setup(const float* __restrict__ dist_emb, const float* __restrict__ Wd,
                            const float* __restrict__ bd, const float* __restrict__ bl,
                            const float* __restrict__ br, float* __restrict__ dWg,
                            float* __restrict__ blr){
  int tid = threadIdx.x;
  for (int idx = tid; idx < NB_ * H_; idx += 256){
    int nb = idx / H_, h = idx - nb * H_;
    float s = bd[h];
    for (int dd = 0; dd < 20; ++dd) s += dist_emb[nb * 20 + dd] * Wd[dd * H_ + h];
    dWg[idx] = s;
  }
  for (int idx = tid; idx < H_; idx += 256){
    blr[idx] = bl[idx];
    blr[H_ + idx] = br[idx];
  }
}

// ---------------- fp32 -> bf16 elementwise (n divisible by 4)
__global__ void cvt_f32_bf16(const float* __restrict__ in, u16* __restrict__ out, int n){
  int idx = (blockIdx.x * 256 + threadIdx.x) * 4;
  if (idx < n){
    float4 v = *(const float4*)(in + idx);
    ushort4 o;
    o.x = f2bf(v.x); o.y = f2bf(v.y); o.z = f2bf(v.z); o.w = f2bf(v.w);
    *(ushort4*)(out + idx) = o;
  }
}

// ---------------- init lr with broadcast bias (cols 0..299 = blr, pad = 0)
__global__ void init_lr(const float* __restrict__ blr, float* __restrict__ lr){
  int idx = blockIdx.x * 256 + threadIdx.x;
  if (idx >= (B_ * K_) * 304) return;
  int col = idx % 304;
  lr[idx] = (col < 300) ? blr[col] : 0.f;
}

// ---------------- bf16 MFMA GEMM, split-K with atomic fp32 accumulation
__global__ __launch_bounds__(256)
void gemm_part_atomic(const u16* __restrict__ A0, const u16* __restrict__ A1,
                      const u16* __restrict__ A2, const u16* __restrict__ BT,
                      int Nn, int Ktot, int klen,
                      float* __restrict__ Out, int ldo){
  __shared__ u16 As[64][72];
  __shared__ u16 Bs[64][72];
  int tid = threadIdx.x;
  int m0 = blockIdx.x * 64, n0 = blockIdx.y * 64;
  int s = blockIdx.z;
  int kbeg = s * klen, kend = kbeg + klen;
  int wave = tid >> 6, lane = tid & 63;
  int wm = wave >> 1, wn = wave & 1;
  int q = lane >> 4, mr = lane & 15;
  f32x4 acc[2][2] = {{{0.f,0.f,0.f,0.f},{0.f,0.f,0.f,0.f}},{{0.f,0.f,0.f,0.f},{0.f,0.f,0.f,0.f}}};
  const u16* Achunks[3] = {A0, A1, A2};
  for (int k0 = kbeg; k0 < kend; k0 += 64){
    const u16* Ap = Achunks[k0 >> 10] + (k0 & 1023);
    for (int c = tid; c < 512; c += 256){
      int row = c >> 3, c8 = c & 7;
      *(uint4*)&As[row][c8 * 8] = *(const uint4*)&Ap[(size_t)(m0 + row) * 1024 + c8 * 8];
    }
    for (int c = tid; c < 512; c += 256){
      int row = c >> 3, c8 = c & 7;
      int n = n0 + row;
      uint4 v; v.x = 0; v.y = 0; v.z = 0; v.w = 0;
      if (n < Nn) v = *(const uint4*)&BT[(size_t)n * Ktot + k0 + c8 * 8];
      *(uint4*)&Bs[row][c8 * 8] = v;
    }
    __syncthreads();
#pragma unroll
    for (int ks = 0; ks < 64; ks += 32){
      bf16x8 a0 = *(const bf16x8*)&As[wm * 32 + mr][ks + q * 8];
      bf16x8 a1 = *(const bf16x8*)&As[wm * 32 + 16 + mr][ks + q * 8];
      bf16x8 b0 = *(const bf16x8*)&Bs[wn * 32 + mr][ks + q * 8];
      bf16x8 b1 = *(const bf16x8*)&Bs[wn * 32 + 16 + mr][ks + q * 8];
      acc[0][0] = __builtin_amdgcn_mfma_f32_16x16x32_bf16(a0, b0, acc[0][0], 0, 0, 0);
      acc[0][1] = __builtin_amdgcn_mfma_f32_16x16x32_bf16(a0, b1, acc[0][1], 0, 0, 0);
      acc[1][0] = __builtin_amdgcn_mfma_f32_16x16x32_bf16(a1, b0, acc[1][0], 0, 0, 0);
      acc[1][1] = __builtin_amdgcn_mfma_f32_16x16x32_bf16(a1, b1, acc[1][1], 0, 0, 0);
    }
    __syncthreads();
  }
#pragma unroll
  for (int mt = 0; mt < 2; ++mt){
#pragma unroll
    for (int nt = 0; nt < 2; ++nt){
      int col = n0 + wn * 32 + nt * 16 + mr;
      if (col >= Nn) continue;
#pragma unroll
      for (int r = 0; r < 4; ++r){
        int row = m0 + wm * 32 + mt * 16 + q * 4 + r;
        atomicAdd(&Out[(size_t)row * ldo + col], acc[mt][nt][r]);
      }
    }
  }
}

// ---------------- epilogue over fp32 accum (ld = 1024); re-zeros accF for next use
// mode 1: outH = bf16(tanh(acc))
// mode 2: outH = bf16(acc)
// mode 3: g = sigmoid(acc + bias[col]); un = g*uin + (1-g)*ctxtin; outF fp32, outH bf16
__global__ __launch_bounds__(256)
void gemm_epi(float* __restrict__ accF, int n,
              const float* __restrict__ bias, int mode,
              float* __restrict__ outF, u16* __restrict__ outH,
              const float* __restrict__ uin, const u16* __restrict__ ctxtin){
  int idx = blockIdx.x * 256 + threadIdx.x;
  if (idx >= n) return;
  float ssum = accF[idx];
  accF[idx] = 0.f;                       // self-zero: next split-K GEMM needs zeroed accum
  if (mode == 1){
    outH[idx] = f2bf(tanhf(ssum));
  } else if (mode == 2){
    outH[idx] = f2bf(ssum);
  } else {
    int col = idx & 1023;
    float g = 1.f / (1.f + expf(-(ssum + bias[col])));
    float uo = uin[idx];
    float ct = bf2f(ctxtin[idx]);
    float un = ct + g * (uo - ct);
    outF[idx] = un;
    outH[idx] = f2bf(un);
  }
}

// ---------------- ctxt via MFMA (32x64 tiles, grid 768):
// c{1,2}[b,i,d] = (P{,T}[b] @ u[b])[i,d] / (sum+eps)
__global__ __launch_bounds__(256)
void ctxt_mfma(const u16* __restrict__ Pbf, const u16* __restrict__ PTbf,
               const u16* __restrict__ uT, const float* __restrict__ rowsum,
               const float* __restrict__ colsum, u16* __restrict__ c1,
               u16* __restrict__ c2){
  __shared__ u16 As[32][72];
  __shared__ u16 Bs[64][72];
  int z = blockIdx.z, b = z >> 1, which = z & 1;
  const u16* A = (which ? PTbf : Pbf) + (size_t)b * K_ * K_;
  const u16* BT = uT + (size_t)b * D_ * K_;
  const float* sums = (which ? colsum : rowsum) + b * K_;
  u16* out = which ? c2 : c1;
  int tid = threadIdx.x;
  int m0 = blockIdx.x * 32, n0 = blockIdx.y * 64;
  int wave = tid >> 6, lane = tid & 63;
  int wm = wave >> 1, wn = wave & 1;
  int q = lane >> 4, mr = lane & 15;
  f32x4 acc[2] = {{0.f,0.f,0.f,0.f},{0.f,0.f,0.f,0.f}};
  for (int k0 = 0; k0 < K_; k0 += 64){
    {
      int row = tid >> 3, c8 = tid & 7;   // 256 threads cover 32x8 uint4 = 2048 elems
      *(uint4*)&As[row][c8 * 8] = *(const uint4*)&A[(size_t)(m0 + row) * K_ + k0 + c8 * 8];
    }
    for (int c = tid; c < 512; c += 256){
      int row = c >> 3, c8 = c & 7;
      *(uint4*)&Bs[row][c8 * 8] = *(const uint4*)&BT[(size_t)(n0 + row) * K_ + k0 + c8 * 8];
    }
    __syncthreads();
#pragma unroll
    for (int ks = 0; ks < 64; ks += 32){
      bf16x8 a  = *(const bf16x8*)&As[wm * 16 + mr][ks + q * 8];
      bf16x8 b0 = *(const bf16x8*)&Bs[wn * 32 + mr][ks + q * 8];
      bf16x8 b1 = *(const bf16x8*)&Bs[wn * 32 + 16 + mr][ks + q * 8];
      acc[0] = __builtin_amdgcn_mfma_f32_16x16x32_bf16(a, b0, acc[0], 0, 0, 0);
      acc[1] = __builtin_amdgcn_mfma_f32_16x16x32_bf16(a, b1, acc[1], 0, 0, 0);
    }
    __syncthreads();
  }
#pragma unroll
  for (int nt = 0; nt < 2; ++nt){
    int col = n0 + wn * 32 + nt * 16 + mr;
#pragma unroll
    for (int r = 0; r < 4; ++r){
      int row = m0 + wm * 16 + q * 4 + r;
      float w = 1.f / (sums[row] + 1e-7f);
      out[((size_t)(b * K_ + row)) * D_ + col] = f2bf(acc[nt][r] * w);
    }
  }
}

// ---------------- scorer (MFMA, wave-autonomous, emits maxS):
// scores[b,i,j,l] (+)= relu(l_i + r_j + dW[bk]) @ Wo + bo ; maxS[b,i,j] = max_l scores
__global__ __launch_bounds__(256)
void scorer_kernel(const float* __restrict__ lr, const float* __restrict__ dWg,
                   const float* __restrict__ Wo, const float* __restrict__ bo,
                   const int* __restrict__ span_begin, const int* __restrict__ span_end,
                   float* __restrict__ scores, float* __restrict__ maxS, int accumulate){
  __shared__ float ldw[NB_ * 160];
  __shared__ u16 h_s[4][16][168];
  int i = blockIdx.x, jblk = blockIdx.y, b = blockIdx.z;
  int tid = threadIdx.x;
  int row_i = b * K_ + i;
  int se = span_end[row_i];
  // stage ldw = l_i + dW (zero pad t>=150), block-cooperative
  for (int e = tid; e < NB_ * 160; e += 256){
    int nb = e / 160, t = e - nb * 160;
    ldw[e] = (t < H_) ? (lr[(size_t)row_i * 304 + t] + dWg[nb * H_ + t]) : 0.f;
  }
  int wave = tid >> 6, lane = tid & 63;
  int q = lane >> 4, mr = lane & 15;
  // Wo^T fragments in registers
  bf16x8 wo_frag[5];
#pragma unroll
  for (int kk = 0; kk < 5; ++kk){
    u16 tmp[8];
#pragma unroll
    for (int e = 0; e < 8; ++e){
      int t = kk * 32 + q * 8 + e;
      float w = (mr < L_ && t < H_) ? Wo[t * L_ + mr] : 0.f;
      tmp[e] = f2bf(w);
    }
    wo_frag[kk] = *(const bf16x8*)tmp;
  }
  // zero this wave's h tail cols [150,160)
  for (int e = lane; e < 16 * 5; e += 64){
    int row = e / 5, w5 = e - row * 5;
    *(unsigned*)&h_s[wave][row][150 + w5 * 2] = 0u;
  }
  float bov = (mr < L_) ? bo[mr] : 0.f;
  int rt = lane >> 2, tq = lane & 3;   // build mapping: 4 lanes per row
  __syncthreads();
#pragma unroll
  for (int p = 0; p < 2; ++p){
    int j0w = jblk * 128 + wave * 32 + p * 16;
    // build h bf16 for this wave's 16 rows
    {
      int j = j0w + rt;
      int bk = bucketf(span_begin[b * K_ + j] - se);
      const float2* rr = (const float2*)(lr + (size_t)(b * K_ + j) * 304 + 150);
      const float2* lw = (const float2*)(ldw + bk * 160);
      u16* hrow = &h_s[wave][rt][0];
      int pp = tq * 19;
#pragma unroll
      for (int s = 0; s < 19; ++s, ++pp){
        if (pp < 75){
          float2 rv = rr[pp];
          float2 lv = lw[pp];
          u16 h0 = f2bf(fmaxf(lv.x + rv.x, 0.f));
          u16 h1 = f2bf(fmaxf(lv.y + rv.y, 0.f));
          *(unsigned*)&hrow[pp * 2] = (unsigned)h0 | ((unsigned)h1 << 16);
        }
      }
    }
    // MFMA: 16 j rows x 16 l cols (12 valid), K=160 (intra-wave LDS dep only)
    f32x4 acc = {0.f, 0.f, 0.f, 0.f};
#pragma unroll
    for (int kk = 0; kk < 5; ++kk){
      bf16x8 a = *(const bf16x8*)&h_s[wave][mr][kk * 32 + q * 8];
      acc = __builtin_amdgcn_mfma_f32_16x16x32_bf16(a, wo_frag[kk], acc, 0, 0, 0);
    }
#pragma unroll
    for (int r = 0; r < 4; ++r){
      int j = j0w + q * 4 + r;
      float v = -3.0e38f;
      if (mr < L_){
        size_t addr = ((size_t)row_i * K_ + j) * L_ + mr;
        v = acc[r] + bov;
        if (accumulate) v += scores[addr];
        scores[addr] = v;
      }
      // masked cross-lane max over the 16-lane label group
      float mx = v;
      mx = fmaxf(mx, __shfl_xor(mx, 1, 16));
      mx = fmaxf(mx, __shfl_xor(mx, 2, 16));
      mx = fmaxf(mx, __shfl_xor(mx, 4, 16));
      mx = fmaxf(mx, __shfl_xor(mx, 8, 16));
      if (mr == 0) maxS[(size_t)row_i * K_ + j] = mx;
    }
  }
}

// ---------------- probs from maxS: p = sigmoid(maxS)*mask ; rowsum ; pbf ; pTbf ; colsum
__global__ __launch_bounds__(384)
void probs_kernel(const float* __restrict__ maxS, const float* __restrict__ mask,
                  u16* __restrict__ pbf, u16* __restrict__ pTbf,
                  float* __restrict__ rowsum, float* __restrict__ colsum){
  int i = blockIdx.x, b = blockIdx.y, j = threadIdx.x;
  size_t base = (size_t)(b * K_ + i) * K_ + j;
  float m = maxS[base];
  float p = mask[base] / (1.f + expf(-m));
  u16 ph = f2bf(p);
  pbf[base] = ph;
  pTbf[((size_t)b * K_ + j) * K_ + i] = ph;                 // fused transP
  atomicAdd(&colsum[b * K_ + j], p);                        // fused colsum
  __shared__ float red[6];
  float s = p;
  for (int o = 32; o > 0; o >>= 1) s += __shfl_down(s, o, 64);
  if ((j & 63) == 0) red[j >> 6] = s;
  __syncthreads();
  if (j == 0){
    float tot = 0.f;
    for (int w = 0; w < 6; ++w) tot += red[w];
    rowsum[b * K_ + i] = tot;
  }
}

// ---------------- float4 copy
__global__ void copy_f4(const float4* __restrict__ src, float4* __restrict__ dst, int n){
  int g = blockIdx.x * 256 + threadIdx.x;
  if (g < n) dst[g] = src[g];
}

// ---------------- overwrite_spans scatter (numpy last-wins for duplicate indices)
__global__ void scatter_kernel(const float* __restrict__ u, const int* __restrict__ prune,
                               const int* __restrict__ span_len, float* __restrict__ outA){
  int blk = blockIdx.x;
  int b = blk / K_, k = blk - b * K_;
  int idx = prune[b * K_ + k];
  bool valid = k < span_len[b];
  bool winner = (k == K_ - 1) || (prune[b * K_ + k + 1] != idx);
  if (!(valid && winner)) return;
  const float4* src = (const float4*)(u + ((size_t)b * K_ + k) * D_);
  float4* dst = (float4*)(outA + ((size_t)b * N_ + idx) * D_);
  for (int t = threadIdx.x; t < D_ / 4; t += blockDim.x) dst[t] = src[t];
}

extern "C" void kernel_launch(void* const* d_in, const int* in_sizes, int n_in,
                              void* d_out, int out_size, void* d_ws, size_t ws_size,
                              hipStream_t stream){
  const float* span_vecs = (const float*)d_in[0];
  const float* all_span  = (const float*)d_in[1];
  const int*   span_begin = (const int*)d_in[2];
  const int*   span_end   = (const int*)d_in[3];
  const float* mask       = (const float*)d_in[4];
  const int*   prune      = (const int*)d_in[5];
  const int*   span_len   = (const int*)d_in[6];
  const float* Wl  = (const float*)d_in[8];
  const float* bl  = (const float*)d_in[9];
  const float* Wr  = (const float*)d_in[10];
  const float* br  = (const float*)d_in[11];
  const float* dist_emb = (const float*)d_in[12];
  const float* Wd  = (const float*)d_in[13];
  const float* bd  = (const float*)d_in[14];
  const float* Wo  = (const float*)d_in[15];
  const float* bo  = (const float*)d_in[16];
  const float* Wff1 = (const float*)d_in[17];
  const float* Wff2 = (const float*)d_in[18];
  const float* Wg  = (const float*)d_in[19];
  const float* bg  = (const float*)d_in[20];

  float* outA = (float*)d_out;                       // (B,N,D)
  float* outU = outA + (size_t)B_ * N_ * D_;         // (B,K,D)
  float* outS = outU + (size_t)B_ * K_ * D_;         // (B,K,K,L)

  char* base = (char*)d_ws;
  size_t off = 0;
  auto alloc = [&](size_t bytes) -> void* {
    void* p = base + off;
    off = (off + bytes + 255) & ~((size_t)255);
    return p;
  };
  u16* WlrT  = (u16*)alloc((size_t)300 * 1024 * sizeof(u16));
  u16* Wff1T = (u16*)alloc((size_t)1024 * 3072 * sizeof(u16));
  u16* Wff2T = (u16*)alloc((size_t)1024 * 1024 * sizeof(u16));
  u16* WgT   = (u16*)alloc((size_t)1024 * 2048 * sizeof(u16));
  float* dWg = (float*)alloc(NB_ * H_ * sizeof(float));
  float* blr = (float*)alloc(300 * sizeof(float));
  float* lr  = (float*)alloc((size_t)B_ * K_ * 304 * sizeof(float));
  float* maxS  = (float*)alloc((size_t)B_ * K_ * K_ * sizeof(float));
  u16* pbf   = (u16*)alloc((size_t)B_ * K_ * K_ * sizeof(u16));
  u16* pTbf  = (u16*)alloc((size_t)B_ * K_ * K_ * sizeof(u16));
  u16* uTbf  = (u16*)alloc((size_t)B_ * D_ * K_ * sizeof(u16));
  float* rowsum = (float*)alloc(B_ * K_ * sizeof(float));
  float* colsum = (float*)alloc(B_ * K_ * sizeof(float));
  u16* ubf0 = (u16*)alloc((size_t)B_ * K_ * D_ * sizeof(u16));
  u16* ubf1 = (u16*)alloc((size_t)B_ * K_ * D_ * sizeof(u16));
  u16* c1bf = (u16*)alloc((size_t)B_ * K_ * D_ * sizeof(u16));
  u16* c2bf = (u16*)alloc((size_t)B_ * K_ * D_ * sizeof(u16));
  u16* tbf  = (u16*)alloc((size_t)B_ * K_ * D_ * sizeof(u16));
  u16* ctxtbf = (u16*)alloc((size_t)B_ * K_ * D_ * sizeof(u16));
  float* uA = (float*)alloc((size_t)B_ * K_ * D_ * sizeof(float));
  float* accF = (float*)alloc((size_t)B_ * K_ * D_ * sizeof(float));  // split-K fp32 accum
  u16* ubf[2] = {ubf0, ubf1};
  (void)ws_size; (void)in_sizes; (void)n_in; (void)out_size;

  dim3 tb(32, 8);
  transpose_f2bf<<<dim3(5, 32), tb, 0, stream>>>(Wl, WlrT, 1024, 150, 1024);
  transpose_f2bf<<<dim3(5, 32), tb, 0, stream>>>(Wr, WlrT + 150 * 1024, 1024, 150, 1024);
  transpose_f2bf<<<dim3(32, 96), tb, 0, stream>>>(Wff1, Wff1T, 3072, 1024, 3072);
  transpose_f2bf<<<dim3(32, 32), tb, 0, stream>>>(Wff2, Wff2T, 1024, 1024, 1024);
  transpose_f2bf<<<dim3(32, 64), tb, 0, stream>>>(Wg, WgT, 2048, 1024, 2048);
  small_setup<<<1, 256, 0, stream>>>(dist_emb, Wd, bd, bl, br, dWg, blr);
  cvt_f32_bf16<<<768, 256, 0, stream>>>(span_vecs, ubf[0], B_ * K_ * D_);
  (void)hipMemsetAsync(accF, 0, (size_t)B_ * K_ * D_ * sizeof(float), stream);  // once; epis self-zero

  // lr = u0 @ [Wl|Wr] + [bl|br]   (split-K=8, 480 blocks, atomic accum into bias-filled lr)
  init_lr<<<912, 256, 0, stream>>>(blr, lr);
  gemm_part_atomic<<<dim3(12, 5, 8), 256, 0, stream>>>(ubf[0], nullptr, nullptr, WlrT,
                                                       300, 1024, 128, lr, 304);
  scorer_kernel<<<dim3(K_, 3, B_), 256, 0, stream>>>(lr, dWg, Wo, bo, span_begin, span_end,
                                                     outS, maxS, 0);

  const float* ucurF = span_vecs;
  int cb = 0;
  float* unexts[2] = {uA, outU};   // it=1 writes u directly into d_out
  for (int it = 0; it < 2; ++it){
    (void)hipMemsetAsync(colsum, 0, B_ * K_ * sizeof(float), stream);
    probs_kernel<<<dim3(K_, B_), 384, 0, stream>>>(maxS, mask, pbf, pTbf, rowsum, colsum);
    transpose_bf<<<dim3(32, 12, B_), tb, 0, stream>>>(ubf[cb], uTbf);
    ctxt_mfma<<<dim3(12, 16, 2 * B_), 256, 0, stream>>>(pbf, pTbf, uTbf, rowsum, colsum,
                                                        c1bf, c2bf);
    // tbf = tanh(cat(u,c1,c2) @ Wff1)   K=3072, split-K=4 (768 blocks)
    gemm_part_atomic<<<dim3(12, 16, 4), 256, 0, stream>>>(ubf[cb], c1bf, c2bf, Wff1T,
                                                          1024, 3072, 768, accF, 1024);
    gemm_epi<<<3072, 256, 0, stream>>>(accF, B_ * K_ * D_, nullptr, 1,
                                       nullptr, tbf, nullptr, nullptr);
    // ctxt = tbf @ Wff2                 K=1024, split-K=4
    gemm_part_atomic<<<dim3(12, 16, 4), 256, 0, stream>>>(tbf, nullptr, nullptr, Wff2T,
                                                          1024, 1024, 256, accF, 1024);
    gemm_epi<<<3072, 256, 0, stream>>>(accF, B_ * K_ * D_, nullptr, 2,
                                       nullptr, ctxtbf, nullptr, nullptr);
    // gate: g = sigmoid(cat(u,ctxt) @ Wg + bg); un = g*u + (1-g)*ctxt   K=2048, split-K=4
    gemm_part_atomic<<<dim3(12, 16, 4), 256, 0, stream>>>(ubf[cb], ctxtbf, nullptr, WgT,
                                                          1024, 2048, 512, accF, 1024);
    float* unext = unexts[it];
    gemm_epi<<<3072, 256, 0, stream>>>(accF, B_ * K_ * D_, bg, 3,
                                       unext, ubf[1 - cb], ucurF, ctxtbf);
    cb = 1 - cb;
    ucurF = unext;
    // lr for next scorer               K=1024, split-K=8
    init_lr<<<912, 256, 0, stream>>>(blr, lr);
    gemm_part_atomic<<<dim3(12, 5, 8), 256, 0, stream>>>(ubf[cb], nullptr, nullptr, WlrT,
                                                         300, 1024, 128, lr, 304);
    scorer_kernel<<<dim3(K_, 3, B_), 256, 0, stream>>>(lr, dWg, Wo, bo, span_begin, span_end,
                                                       outS, maxS, 1);
  }

  copy_f4<<<8192, 256, 0, stream>>>((const float4*)all_span, (float4*)outA, (B_ * N_ * D_) / 4);
  // ucurF == outU after it=1 — no final u copy needed
  scatter_kernel<<<B_ * K_, 256, 0, stream>>>(ucurF, prune, span_len, outA);
}